// Round 2
// baseline (423.914 us; speedup 1.0000x reference)
//
#include <hip/hip_runtime.h>
#include <cstdint>
#include <cstddef>

// ---------------- types / helpers ----------------
typedef __attribute__((ext_vector_type(8))) __bf16 bf16x8;
typedef __attribute__((ext_vector_type(4))) float  f32x4;

#define MFMA16(a, b, c) __builtin_amdgcn_mfma_f32_16x16x32_bf16((a), (b), (c), 0, 0, 0)

#define T_SEQ 4096
#define NHEADS 8
#define DH 64
#define NEG_INF (-__builtin_huge_valf())
// 1/sqrt(64) * log2(e)  (softmax done in exp2 domain)
#define SCALE_Q 0.18033688011112042f

__device__ __forceinline__ unsigned short f2bf(float f) {
  unsigned int u = __float_as_uint(f);
  u += 0x7fffu + ((u >> 16) & 1u);
  return (unsigned short)(u >> 16);
}

// ---------------- conversion kernels ----------------
__global__ void cvt_x_kernel(const float* __restrict__ x,
                             unsigned short* __restrict__ xb, int n4) {
  int i = blockIdx.x * blockDim.x + threadIdx.x;
  if (i >= n4) return;
  float4 v = ((const float4*)x)[i];
  ushort4 o;
  o.x = f2bf(v.x); o.y = f2bf(v.y); o.z = f2bf(v.z); o.w = f2bf(v.w);
  ((ushort4*)xb)[i] = o;
}

// w [512][N] (K=512 rows) -> wT [N][512] bf16
__global__ void cvt_T_kernel(const float* __restrict__ w,
                             unsigned short* __restrict__ wT, int N, int total) {
  int i = blockIdx.x * blockDim.x + threadIdx.x;
  if (i >= total) return;
  int n = i >> 9, k = i & 511;
  wT[i] = f2bf(w[(size_t)k * N + n]);
}

// ---------------- GEMM: C = A[M,K] * BT[N,K]^T + bias ----------------
// 128x128 block tile, BK=32, 4 waves (each a 64x64 quadrant), 16x16x32 MFMA.
// EPI==0: QKV epilogue (q/k -> [B*H][T][64], V -> transposed [B*H][64][T])
// EPI==1: fp32 output [M][512] with bias
template <int EPI>
__global__ __launch_bounds__(256) void gemm_bt(
    const unsigned short* __restrict__ A,
    const unsigned short* __restrict__ BT,
    const float* __restrict__ bias,
    float* __restrict__ outf,
    unsigned short* __restrict__ oq,
    unsigned short* __restrict__ ok,
    unsigned short* __restrict__ ovT,
    int K) {
  __shared__ alignas(16) unsigned short As[128 * 32];
  __shared__ alignas(16) unsigned short Bs[128 * 32];

  const int t = threadIdx.x;
  const int lane = t & 63;
  const int w = t >> 6;
  const int wr = (w >> 1) * 64;
  const int wc = (w & 1) * 64;
  const int g = lane >> 4, c = lane & 15;
  const int row0 = blockIdx.y * 128, col0 = blockIdx.x * 128;

  const int crow = t >> 2;          // 0..63
  const int ccol = (t & 3) * 8;     // 0,8,16,24
  const unsigned short* Ag0 = A + (size_t)(row0 + crow) * K + ccol;
  const unsigned short* Ag1 = A + (size_t)(row0 + 64 + crow) * K + ccol;
  const unsigned short* Bg0 = BT + (size_t)(col0 + crow) * K + ccol;
  const unsigned short* Bg1 = BT + (size_t)(col0 + 64 + crow) * K + ccol;

  f32x4 acc[4][4] = {};

  for (int k0 = 0; k0 < K; k0 += 32) {
    int4 a0 = *(const int4*)(Ag0 + k0);
    int4 a1 = *(const int4*)(Ag1 + k0);
    int4 b0 = *(const int4*)(Bg0 + k0);
    int4 b1 = *(const int4*)(Bg1 + k0);
    __syncthreads();
    *(int4*)&As[crow * 32 + ccol] = a0;
    *(int4*)&As[(64 + crow) * 32 + ccol] = a1;
    *(int4*)&Bs[crow * 32 + ccol] = b0;
    *(int4*)&Bs[(64 + crow) * 32 + ccol] = b1;
    __syncthreads();

    bf16x8 af[4], bfr[4];
#pragma unroll
    for (int m = 0; m < 4; ++m)
      af[m] = *(const bf16x8*)&As[(wr + m * 16 + c) * 32 + g * 8];
#pragma unroll
    for (int n = 0; n < 4; ++n)
      bfr[n] = *(const bf16x8*)&Bs[(wc + n * 16 + c) * 32 + g * 8];
#pragma unroll
    for (int m = 0; m < 4; ++m)
#pragma unroll
      for (int n = 0; n < 4; ++n)
        acc[m][n] = MFMA16(af[m], bfr[n], acc[m][n]);
  }

  // epilogue. D layout: row = g*4 + i, col = c (verified m89/m91 mapping)
#pragma unroll
  for (int m = 0; m < 4; ++m) {
#pragma unroll
    for (int n = 0; n < 4; ++n) {
      const int col = col0 + wc + n * 16 + c;
      const float bv = bias[col];
      if constexpr (EPI == 0) {
        const int which = col >> 9;          // wave-uniform (depends on block,n)
        const int h = (col >> 6) & 7;
        const int dh = col & 63;
        const int r0 = row0 + wr + m * 16 + g * 4;
        const int bb = r0 >> 12;             // r0 / T_SEQ (4 rows never cross)
        const int tt0 = r0 & 4095;
        if (which == 2) {
          // V transposed: vT[(bb*H + h)*64 + dh][tt0..tt0+3] -- contiguous
          ushort4 pk;
          pk.x = f2bf(acc[m][n][0] + bv);
          pk.y = f2bf(acc[m][n][1] + bv);
          pk.z = f2bf(acc[m][n][2] + bv);
          pk.w = f2bf(acc[m][n][3] + bv);
          *(ushort4*)&ovT[((size_t)((bb * NHEADS + h) * DH + dh)) * T_SEQ + tt0] = pk;
        } else {
          unsigned short* dst = (which == 0) ? oq : ok;
          const float sc = (which == 0) ? SCALE_Q : 1.0f;
#pragma unroll
          for (int i = 0; i < 4; ++i) {
            const size_t idx =
                ((size_t)((bb * NHEADS + h) * T_SEQ + tt0 + i)) * DH + dh;
            dst[idx] = f2bf((acc[m][n][i] + bv) * sc);
          }
        }
      } else {
#pragma unroll
        for (int i = 0; i < 4; ++i) {
          const int row = row0 + wr + m * 16 + g * 4 + i;
          outf[(size_t)row * 512 + col] = acc[m][n][i] + bv;
        }
      }
    }
  }
}

// ---------------- flash attention (causal) ----------------
// grid (B*H, T/64). 4 waves/block, each wave owns 16 q-rows. KV tiles of 64.
// V is consumed transposed: vT[bh][d][t] so the PV B-fragment is one
// contiguous bf16x8 per lane.
__global__ __launch_bounds__(256) void attn_kernel(
    const unsigned short* __restrict__ qb,
    const unsigned short* __restrict__ kb,
    const unsigned short* __restrict__ vtb,
    unsigned short* __restrict__ yb) {
  const int bh = blockIdx.x;
  const int y = blockIdx.y;
  // causal load-balance: interleave heavy (large qblk) and light blocks
  const int qblk = (y & 1) ? (63 - (y >> 1)) : (y >> 1);
  const int w = threadIdx.x >> 6;
  const int lane = threadIdx.x & 63;
  const int g = lane >> 4, c = lane & 15;
  const int qw0 = qblk * 64 + w * 16;

  const unsigned short* Qp = qb + (size_t)bh * T_SEQ * DH;
  const unsigned short* Kp = kb + (size_t)bh * T_SEQ * DH;
  const unsigned short* VTp = vtb + (size_t)bh * DH * T_SEQ;

  // per-wave P buffer: 16 rows x 64 keys, padded to 72 (2-way conflict max)
  __shared__ alignas(16) unsigned short Plds[4][16 * 72];

  // Q fragments (A-operand): row = c, k = g*8..g*8+7 (+32 for second frag)
  bf16x8 qf0 = *(const bf16x8*)&Qp[(size_t)(qw0 + c) * DH + g * 8];
  bf16x8 qf1 = *(const bf16x8*)&Qp[(size_t)(qw0 + c) * DH + 32 + g * 8];

  f32x4 acc[4] = {};
  float mi[4] = {NEG_INF, NEG_INF, NEG_INF, NEG_INF};
  float li[4] = {0.f, 0.f, 0.f, 0.f};

  const int jend = qw0 + 15;  // last needed key (inclusive)
  for (int j0 = 0; j0 <= jend; j0 += 64) {
    // S tile: 16 q x 64 keys, four 16-key column sub-tiles
    f32x4 s[4];
#pragma unroll
    for (int ks = 0; ks < 4; ++ks) {
      const unsigned short* Kr = &Kp[(size_t)(j0 + ks * 16 + c) * DH + g * 8];
      bf16x8 kf0 = *(const bf16x8*)Kr;
      bf16x8 kf1 = *(const bf16x8*)(Kr + 32);
      f32x4 z = {0.f, 0.f, 0.f, 0.f};
      z = MFMA16(qf0, kf0, z);
      z = MFMA16(qf1, kf1, z);
      s[ks] = z;
    }

    if (j0 + 63 > qw0) {  // tile touches/passes the diagonal: causal mask
#pragma unroll
      for (int ks = 0; ks < 4; ++ks)
#pragma unroll
        for (int i = 0; i < 4; ++i) {
          const int key = j0 + ks * 16 + c;
          if (key > qw0 + g * 4 + i) s[ks][i] = NEG_INF;
        }
    }

    // online softmax (exp2 domain; scale folded into Q)
    float mt[4], sc[4];
#pragma unroll
    for (int i = 0; i < 4; ++i)
      mt[i] = fmaxf(fmaxf(s[0][i], s[1][i]), fmaxf(s[2][i], s[3][i]));
#pragma unroll
    for (int off = 1; off < 16; off <<= 1)
#pragma unroll
      for (int i = 0; i < 4; ++i) mt[i] = fmaxf(mt[i], __shfl_xor(mt[i], off));
#pragma unroll
    for (int i = 0; i < 4; ++i) {
      const float mn = fmaxf(mi[i], mt[i]);
      sc[i] = exp2f(mi[i] - mn);
      mi[i] = mn;
    }
    float ls[4] = {0.f, 0.f, 0.f, 0.f};
#pragma unroll
    for (int ks = 0; ks < 4; ++ks)
#pragma unroll
      for (int i = 0; i < 4; ++i) {
        const float p = exp2f(s[ks][i] - mi[i]);
        ls[i] += p;
        Plds[w][(g * 4 + i) * 72 + ks * 16 + c] = f2bf(p);
      }
#pragma unroll
    for (int off = 1; off < 16; off <<= 1)
#pragma unroll
      for (int i = 0; i < 4; ++i) ls[i] += __shfl_xor(ls[i], off);
#pragma unroll
    for (int i = 0; i < 4; ++i) li[i] = li[i] * sc[i] + ls[i];
#pragma unroll
    for (int dt = 0; dt < 4; ++dt)
#pragma unroll
      for (int i = 0; i < 4; ++i) acc[dt][i] *= sc[i];

    // wave-private LDS RAW: make sure writes land before the A-frag read
    asm volatile("s_waitcnt lgkmcnt(0)" ::: "memory");

    // P A-fragments: row = c, k(=key) = g*8..+7 and 32+g*8..+7
    bf16x8 pf0 = *(const bf16x8*)&Plds[w][c * 72 + g * 8];
    bf16x8 pf1 = *(const bf16x8*)&Plds[w][c * 72 + 32 + g * 8];

    // PV: B-frag = vT[d = dt*16+c][key = j0+g*8..+7] -- contiguous 16B/lane
#pragma unroll
    for (int dt = 0; dt < 4; ++dt) {
      const unsigned short* Vr = &VTp[(size_t)(dt * 16 + c) * T_SEQ + j0 + g * 8];
      bf16x8 vf0 = *(const bf16x8*)Vr;
      bf16x8 vf1 = *(const bf16x8*)(Vr + 32);
      acc[dt] = MFMA16(pf0, vf0, acc[dt]);
      acc[dt] = MFMA16(pf1, vf1, acc[dt]);
    }
  }

  // normalize + store to y_flat[(b*T + q)*512 + h*64 + d] as bf16
  const int bb = bh >> 3, h = bh & 7;
#pragma unroll
  for (int i = 0; i < 4; ++i) {
    const float inv = 1.0f / li[i];
    const int qq = qw0 + g * 4 + i;
    const size_t base = ((size_t)(bb * T_SEQ + qq)) * 512 + h * DH;
#pragma unroll
    for (int dt = 0; dt < 4; ++dt)
      yb[base + dt * 16 + c] = f2bf(acc[dt][i] * inv);
  }
}

// ---------------- launch ----------------
extern "C" void kernel_launch(void* const* d_in, const int* in_sizes, int n_in,
                              void* d_out, int out_size, void* d_ws, size_t ws_size,
                              hipStream_t stream) {
  const float* x     = (const float*)d_in[0];
  const float* w_qkv = (const float*)d_in[1];
  const float* b_qkv = (const float*)d_in[2];
  const float* w_out = (const float*)d_in[3];
  const float* b_out = (const float*)d_in[4];
  float* out = (float*)d_out;

  char* p = (char*)d_ws;
  unsigned short* xb    = (unsigned short*)p; p += (size_t)8192 * 512 * 2;
  unsigned short* wqkvT = (unsigned short*)p; p += (size_t)1536 * 512 * 2;
  unsigned short* woutT = (unsigned short*)p; p += (size_t)512 * 512 * 2;
  unsigned short* qbuf  = (unsigned short*)p; p += (size_t)16 * T_SEQ * DH * 2;
  unsigned short* kbuf  = (unsigned short*)p; p += (size_t)16 * T_SEQ * DH * 2;
  unsigned short* vtbuf = (unsigned short*)p; p += (size_t)16 * T_SEQ * DH * 2;
  unsigned short* ybuf  = (unsigned short*)p; p += (size_t)8192 * 512 * 2;

  cvt_x_kernel<<<4096, 256, 0, stream>>>(x, xb, 8192 * 512 / 4);
  cvt_T_kernel<<<3072, 256, 0, stream>>>(w_qkv, wqkvT, 1536, 1536 * 512);
  cvt_T_kernel<<<1024, 256, 0, stream>>>(w_out, woutT, 512, 512 * 512);

  // QKV projection: M=8192, N=1536, K=512
  gemm_bt<0><<<dim3(12, 64), 256, 0, stream>>>(xb, wqkvT, b_qkv, nullptr,
                                               qbuf, kbuf, vtbuf, 512);
  // attention
  attn_kernel<<<dim3(16, 64), 256, 0, stream>>>(qbuf, kbuf, vtbuf, ybuf);
  // output projection: M=8192, N=512, K=512
  gemm_bt<1><<<dim3(4, 64), 256, 0, stream>>>(ybuf, woutT, b_out, out,
                                              nullptr, nullptr, nullptr, 512);
}

// Round 6
// 254.349 us; speedup vs baseline: 1.6667x; 1.6667x over previous
//
#include <hip/hip_runtime.h>
#include <cstdint>
#include <cstddef>

// ---------------- types / helpers ----------------
typedef __attribute__((ext_vector_type(8))) __bf16 bf16x8;
typedef __attribute__((ext_vector_type(4))) float  f32x4;

#define MFMA16(a, b, c) __builtin_amdgcn_mfma_f32_16x16x32_bf16((a), (b), (c), 0, 0, 0)

#define T_SEQ 4096
#define NHEADS 8
#define DH 64
#define NEG_INF (-__builtin_huge_valf())
// 1/sqrt(64) * log2(e)  (softmax done in exp2 domain)
#define SCALE_Q 0.18033688011112042f

__device__ __forceinline__ unsigned short f2bf(float f) {
  unsigned int u = __float_as_uint(f);
  u += 0x7fffu + ((u >> 16) & 1u);
  return (unsigned short)(u >> 16);
}

// async global->LDS, 16B per lane. LDS dest = uniform base + lane*16.
__device__ __forceinline__ void gload16(const unsigned short* g, unsigned short* l) {
  __builtin_amdgcn_global_load_lds(
      (const __attribute__((address_space(1))) unsigned short*)g,
      (__attribute__((address_space(3))) unsigned short*)l, 16, 0, 0);
}

// ---------------- conversion kernels ----------------
__global__ void cvt_x_kernel(const float* __restrict__ x,
                             unsigned short* __restrict__ xb, int n4) {
  int i = blockIdx.x * blockDim.x + threadIdx.x;
  if (i >= n4) return;
  float4 v = ((const float4*)x)[i];
  ushort4 o;
  o.x = f2bf(v.x); o.y = f2bf(v.y); o.z = f2bf(v.z); o.w = f2bf(v.w);
  ((ushort4*)xb)[i] = o;
}

// w [512][N] (K=512 rows) -> wT [N][512] bf16
__global__ void cvt_T_kernel(const float* __restrict__ w,
                             unsigned short* __restrict__ wT, int N, int total) {
  int i = blockIdx.x * blockDim.x + threadIdx.x;
  if (i >= total) return;
  int n = i >> 9, k = i & 511;
  wT[i] = f2bf(w[(size_t)k * N + n]);
}

// ---------------- GEMM: C = A[M,K] * BT[N,K]^T + bias ----------------
// 128x128 block tile, BK=32, 4 waves (each a 64x64 quadrant), 16x16x32 MFMA.
// EPI==0: QKV epilogue (q/k -> [B*H][T][64], V -> transposed [B*H][64][T])
// EPI==1: fp32 output [M][512] with bias
template <int EPI>
__global__ __launch_bounds__(256) void gemm_bt(
    const unsigned short* __restrict__ A,
    const unsigned short* __restrict__ BT,
    const float* __restrict__ bias,
    float* __restrict__ outf,
    unsigned short* __restrict__ oq,
    unsigned short* __restrict__ ok,
    unsigned short* __restrict__ ovT,
    int K) {
  __shared__ alignas(16) unsigned short As[128 * 32];
  __shared__ alignas(16) unsigned short Bs[128 * 32];

  const int t = threadIdx.x;
  const int lane = t & 63;
  const int w = t >> 6;
  const int wr = (w >> 1) * 64;
  const int wc = (w & 1) * 64;
  const int g = lane >> 4, c = lane & 15;
  const int row0 = blockIdx.y * 128, col0 = blockIdx.x * 128;

  const int crow = t >> 2;          // 0..63
  const int ccol = (t & 3) * 8;     // 0,8,16,24
  const unsigned short* Ag0 = A + (size_t)(row0 + crow) * K + ccol;
  const unsigned short* Ag1 = A + (size_t)(row0 + 64 + crow) * K + ccol;
  const unsigned short* Bg0 = BT + (size_t)(col0 + crow) * K + ccol;
  const unsigned short* Bg1 = BT + (size_t)(col0 + 64 + crow) * K + ccol;

  f32x4 acc[4][4] = {};

  for (int k0 = 0; k0 < K; k0 += 32) {
    int4 a0 = *(const int4*)(Ag0 + k0);
    int4 a1 = *(const int4*)(Ag1 + k0);
    int4 b0 = *(const int4*)(Bg0 + k0);
    int4 b1 = *(const int4*)(Bg1 + k0);
    __syncthreads();
    *(int4*)&As[crow * 32 + ccol] = a0;
    *(int4*)&As[(64 + crow) * 32 + ccol] = a1;
    *(int4*)&Bs[crow * 32 + ccol] = b0;
    *(int4*)&Bs[(64 + crow) * 32 + ccol] = b1;
    __syncthreads();

    bf16x8 af[4], bfr[4];
#pragma unroll
    for (int m = 0; m < 4; ++m)
      af[m] = *(const bf16x8*)&As[(wr + m * 16 + c) * 32 + g * 8];
#pragma unroll
    for (int n = 0; n < 4; ++n)
      bfr[n] = *(const bf16x8*)&Bs[(wc + n * 16 + c) * 32 + g * 8];
#pragma unroll
    for (int m = 0; m < 4; ++m)
#pragma unroll
      for (int n = 0; n < 4; ++n)
        acc[m][n] = MFMA16(af[m], bfr[n], acc[m][n]);
  }

  // epilogue. D layout: row = g*4 + i, col = c (verified m89/m91 mapping)
#pragma unroll
  for (int m = 0; m < 4; ++m) {
#pragma unroll
    for (int n = 0; n < 4; ++n) {
      const int col = col0 + wc + n * 16 + c;
      const float bv = bias[col];
      if constexpr (EPI == 0) {
        const int which = col >> 9;          // wave-uniform (depends on block,n)
        const int h = (col >> 6) & 7;
        const int dh = col & 63;
        const int r0 = row0 + wr + m * 16 + g * 4;
        const int bb = r0 >> 12;             // r0 / T_SEQ (4 rows never cross)
        const int tt0 = r0 & 4095;
        if (which == 2) {
          // V transposed: vT[(bb*H + h)*64 + dh][tt0..tt0+3] -- contiguous
          ushort4 pk;
          pk.x = f2bf(acc[m][n][0] + bv);
          pk.y = f2bf(acc[m][n][1] + bv);
          pk.z = f2bf(acc[m][n][2] + bv);
          pk.w = f2bf(acc[m][n][3] + bv);
          *(ushort4*)&ovT[((size_t)((bb * NHEADS + h) * DH + dh)) * T_SEQ + tt0] = pk;
        } else {
          unsigned short* dst = (which == 0) ? oq : ok;
          const float sc = (which == 0) ? SCALE_Q : 1.0f;
#pragma unroll
          for (int i = 0; i < 4; ++i) {
            const size_t idx =
                ((size_t)((bb * NHEADS + h) * T_SEQ + tt0 + i)) * DH + dh;
            dst[idx] = f2bf((acc[m][n][i] + bv) * sc);
          }
        }
      } else {
#pragma unroll
        for (int i = 0; i < 4; ++i) {
          const int row = row0 + wr + m * 16 + g * 4 + i;
          outf[(size_t)row * 512 + col] = acc[m][n][i] + bv;
        }
      }
    }
  }
}

// ---------------- flash attention (causal) ----------------
// grid (B*H, T/64). 4 waves/block, each wave owns 16 q-rows. KV tiles of 64
// staged block-wide in LDS via global_load_lds, double-buffered, with
// XOR-swizzled rows (pre-swizzled global source + swizzled ds_read).
__global__ __launch_bounds__(256) void attn_kernel(
    const unsigned short* __restrict__ qb,
    const unsigned short* __restrict__ kb,
    const unsigned short* __restrict__ vtb,
    unsigned short* __restrict__ yb) {
  const int bh = blockIdx.x;
  const int y = blockIdx.y;
  // causal load-balance: interleave heavy (large qblk) and light blocks
  const int qblk = (y & 1) ? (63 - (y >> 1)) : (y >> 1);
  const int w = threadIdx.x >> 6;
  const int lane = threadIdx.x & 63;
  const int g = lane >> 4, c = lane & 15;
  const int qw0 = qblk * 64 + w * 16;

  // K tile: rows = key (64), cols = d (64, 128B). V tile: rows = d, cols = t.
  __shared__ alignas(16) unsigned short Ks[2][64 * 64];
  __shared__ alignas(16) unsigned short Vs[2][64 * 64];
  __shared__ alignas(16) unsigned short Plds[4][16 * 64];

  const unsigned short* Qp  = qb + (size_t)bh * T_SEQ * DH;
  const unsigned short* Kp  = kb + (size_t)bh * T_SEQ * DH;
  const unsigned short* VTp = vtb + (size_t)bh * DH * T_SEQ;

  // staging: wave w stages LDS rows 16w..16w+15 of both tiles (2 gloads each).
  // source column pre-swizzled: row r keeps byte-col cb at cb ^ ((r&7)<<4);
  // gload instr writes rows q*8+l8 linearly, so swizzle = 8*(lc ^ l8) elems.
  const int l8 = lane >> 3, lc = lane & 7;
  const int swzE = 8 * (lc ^ l8);
  const unsigned short* Ksrc0 = Kp + (size_t)(16 * w + l8) * DH + swzE;
  const unsigned short* Ksrc1 = Kp + (size_t)(16 * w + 8 + l8) * DH + swzE;
  const unsigned short* Vsrc0 = VTp + (size_t)(16 * w + l8) * T_SEQ + swzE;
  const unsigned short* Vsrc1 = VTp + (size_t)(16 * w + 8 + l8) * T_SEQ + swzE;

#define STAGE(B, J0) do {                                              \
    gload16(Ksrc0 + (size_t)(J0) * DH, &Ks[B][(2 * w) * 512]);         \
    gload16(Ksrc1 + (size_t)(J0) * DH, &Ks[B][(2 * w + 1) * 512]);     \
    gload16(Vsrc0 + (J0), &Vs[B][(2 * w) * 512]);                      \
    gload16(Vsrc1 + (J0), &Vs[B][(2 * w + 1) * 512]);                  \
  } while (0)

  // Q fragments (A-operand): row = c, k = g*8..g*8+7 (+32 for second frag)
  bf16x8 qf0 = *(const bf16x8*)&Qp[(size_t)(qw0 + c) * DH + g * 8];
  bf16x8 qf1 = *(const bf16x8*)&Qp[(size_t)(qw0 + c) * DH + 32 + g * 8];

  f32x4 acc[4] = {};
  float mi[4] = {NEG_INF, NEG_INF, NEG_INF, NEG_INF};
  float li[4] = {0.f, 0.f, 0.f, 0.f};

  const int nt = qblk + 1;  // all waves run the same tile count, mask handles tail
  STAGE(0, 0);
  __syncthreads();  // compiler drains vmcnt(0) before s_barrier
  int cur = 0;
  const int swb = (c & 7) << 4;  // read-side xor (bytes)
  char* Pw = (char*)&Plds[w][0];

  for (int t = 0; t < nt; ++t) {
    if (t + 1 < nt) STAGE(cur ^ 1, (t + 1) * 64);

    const char* Kb = (const char*)&Ks[cur][0];
    const char* Vb = (const char*)&Vs[cur][0];

    // S tile: 16 q x 64 keys, four 16-key column sub-tiles
    f32x4 s[4];
#pragma unroll
    for (int ks = 0; ks < 4; ++ks) {
      const int rb = (ks * 16 + c) * 128;
      bf16x8 kf0 = *(const bf16x8*)(Kb + rb + ((16 * g) ^ swb));
      bf16x8 kf1 = *(const bf16x8*)(Kb + rb + ((64 + 16 * g) ^ swb));
      f32x4 z = {0.f, 0.f, 0.f, 0.f};
      z = MFMA16(qf0, kf0, z);
      z = MFMA16(qf1, kf1, z);
      s[ks] = z;
    }

    // V fragments early -- independent of softmax, overlap ds latency
    bf16x8 vf0[4], vf1[4];
#pragma unroll
    for (int dt = 0; dt < 4; ++dt) {
      const int rb = (dt * 16 + c) * 128;
      vf0[dt] = *(const bf16x8*)(Vb + rb + ((16 * g) ^ swb));
      vf1[dt] = *(const bf16x8*)(Vb + rb + ((64 + 16 * g) ^ swb));
    }

    if (t == qblk) {  // diagonal tile: causal mask
#pragma unroll
      for (int ks = 0; ks < 4; ++ks)
#pragma unroll
        for (int i = 0; i < 4; ++i) {
          const int key = t * 64 + ks * 16 + c;
          if (key > qw0 + g * 4 + i) s[ks][i] = NEG_INF;
        }
    }

    // online softmax (exp2 domain; scale folded into Q)
    float mt[4], sc[4];
#pragma unroll
    for (int i = 0; i < 4; ++i)
      mt[i] = fmaxf(fmaxf(s[0][i], s[1][i]), fmaxf(s[2][i], s[3][i]));
#pragma unroll
    for (int off = 1; off < 16; off <<= 1)
#pragma unroll
      for (int i = 0; i < 4; ++i) mt[i] = fmaxf(mt[i], __shfl_xor(mt[i], off));
#pragma unroll
    for (int i = 0; i < 4; ++i) {
      const float mn = fmaxf(mi[i], mt[i]);
      sc[i] = exp2f(mi[i] - mn);
      mi[i] = mn;
    }
    float ls[4] = {0.f, 0.f, 0.f, 0.f};
#pragma unroll
    for (int ks = 0; ks < 4; ++ks)
#pragma unroll
      for (int i = 0; i < 4; ++i) {
        const float p = exp2f(s[ks][i] - mi[i]);
        ls[i] += p;
        const int prow = g * 4 + i;
        *(unsigned short*)(Pw + prow * 128 +
                           (((ks * 16 + c) * 2) ^ ((prow & 7) << 4))) = f2bf(p);
      }
#pragma unroll
    for (int off = 1; off < 16; off <<= 1)
#pragma unroll
      for (int i = 0; i < 4; ++i) ls[i] += __shfl_xor(ls[i], off);
#pragma unroll
    for (int i = 0; i < 4; ++i) li[i] = li[i] * sc[i] + ls[i];
#pragma unroll
    for (int dt = 0; dt < 4; ++dt)
#pragma unroll
      for (int i = 0; i < 4; ++i) acc[dt][i] *= sc[i];

    // wave-private LDS RAW: P stores must land before the A-frag read
    asm volatile("s_waitcnt lgkmcnt(0)" ::: "memory");

    bf16x8 pf0 = *(const bf16x8*)(Pw + c * 128 + ((16 * g) ^ swb));
    bf16x8 pf1 = *(const bf16x8*)(Pw + c * 128 + ((64 + 16 * g) ^ swb));

#pragma unroll
    for (int dt = 0; dt < 4; ++dt) {
      acc[dt] = MFMA16(pf0, vf0[dt], acc[dt]);
      acc[dt] = MFMA16(pf1, vf1[dt], acc[dt]);
    }

    // barrier: publishes prefetched tile (vmcnt drain) + protects buf reuse
    __syncthreads();
    cur ^= 1;
  }
#undef STAGE

  // normalize + store to y_flat[(b*T + q)*512 + h*64 + d] as bf16
  const int bb = bh >> 3, h = bh & 7;
#pragma unroll
  for (int i = 0; i < 4; ++i) {
    const float inv = 1.0f / li[i];
    const int qq = qw0 + g * 4 + i;
    const size_t base = ((size_t)(bb * T_SEQ + qq)) * 512 + h * DH;
#pragma unroll
    for (int dt = 0; dt < 4; ++dt)
      yb[base + dt * 16 + c] = f2bf(acc[dt][i] * inv);
  }
}

// ---------------- launch ----------------
extern "C" void kernel_launch(void* const* d_in, const int* in_sizes, int n_in,
                              void* d_out, int out_size, void* d_ws, size_t ws_size,
                              hipStream_t stream) {
  const float* x     = (const float*)d_in[0];
  const float* w_qkv = (const float*)d_in[1];
  const float* b_qkv = (const float*)d_in[2];
  const float* w_out = (const float*)d_in[3];
  const float* b_out = (const float*)d_in[4];
  float* out = (float*)d_out;

  char* p = (char*)d_ws;
  unsigned short* xb    = (unsigned short*)p; p += (size_t)8192 * 512 * 2;
  unsigned short* wqkvT = (unsigned short*)p; p += (size_t)1536 * 512 * 2;
  unsigned short* woutT = (unsigned short*)p; p += (size_t)512 * 512 * 2;
  unsigned short* qbuf  = (unsigned short*)p; p += (size_t)16 * T_SEQ * DH * 2;
  unsigned short* kbuf  = (unsigned short*)p; p += (size_t)16 * T_SEQ * DH * 2;
  unsigned short* vtbuf = (unsigned short*)p; p += (size_t)16 * T_SEQ * DH * 2;
  unsigned short* ybuf  = (unsigned short*)p; p += (size_t)8192 * 512 * 2;

  cvt_x_kernel<<<4096, 256, 0, stream>>>(x, xb, 8192 * 512 / 4);
  cvt_T_kernel<<<3072, 256, 0, stream>>>(w_qkv, wqkvT, 1536, 1536 * 512);
  cvt_T_kernel<<<1024, 256, 0, stream>>>(w_out, woutT, 512, 512 * 512);

  // QKV projection: M=8192, N=1536, K=512
  gemm_bt<0><<<dim3(12, 64), 256, 0, stream>>>(xb, wqkvT, b_qkv, nullptr,
                                               qbuf, kbuf, vtbuf, 512);
  // attention
  attn_kernel<<<dim3(16, 64), 256, 0, stream>>>(qbuf, kbuf, vtbuf, ybuf);
  // output projection: M=8192, N=512, K=512
  gemm_bt<1><<<dim3(4, 64), 256, 0, stream>>>(ybuf, woutT, b_out, out,
                                              nullptr, nullptr, nullptr, 512);
}

// Round 7
// 197.510 us; speedup vs baseline: 2.1463x; 1.2878x over previous
//
#include <hip/hip_runtime.h>
#include <cstdint>
#include <cstddef>

// ---------------- types / helpers ----------------
typedef __attribute__((ext_vector_type(8))) __bf16 bf16x8;
typedef __attribute__((ext_vector_type(4))) float  f32x4;

#define MFMA16(a, b, c) __builtin_amdgcn_mfma_f32_16x16x32_bf16((a), (b), (c), 0, 0, 0)

#define T_SEQ 4096
#define NHEADS 8
#define DH 64
#define NEG_INF (-__builtin_huge_valf())
// 1/sqrt(64) * log2(e)  (softmax done in exp2 domain)
#define SCALE_Q 0.18033688011112042f

__device__ __forceinline__ unsigned short f2bf(float f) {
  unsigned int u = __float_as_uint(f);
  u += 0x7fffu + ((u >> 16) & 1u);
  return (unsigned short)(u >> 16);
}

// pack two f32 -> two bf16 in one u32 (round-half-up; a = low half)
__device__ __forceinline__ unsigned int pack_bf2(float a, float b) {
  unsigned int au = __float_as_uint(a) + 0x8000u;
  unsigned int bu = __float_as_uint(b) + 0x8000u;
  return (au >> 16) | (bu & 0xffff0000u);
}

// async global->LDS, 16B per lane. LDS dest = uniform base + lane*16.
__device__ __forceinline__ void gload16(const unsigned short* g, unsigned short* l) {
  __builtin_amdgcn_global_load_lds(
      (const __attribute__((address_space(1))) unsigned short*)g,
      (__attribute__((address_space(3))) unsigned short*)l, 16, 0, 0);
}

// ---------------- conversion kernels ----------------
__global__ void cvt_x_kernel(const float* __restrict__ x,
                             unsigned short* __restrict__ xb, int n4) {
  int i = blockIdx.x * blockDim.x + threadIdx.x;
  if (i >= n4) return;
  float4 v = ((const float4*)x)[i];
  ushort4 o;
  o.x = f2bf(v.x); o.y = f2bf(v.y); o.z = f2bf(v.z); o.w = f2bf(v.w);
  ((ushort4*)xb)[i] = o;
}

// w [512][N] (K=512 rows) -> wT [N][512] bf16
__global__ void cvt_T_kernel(const float* __restrict__ w,
                             unsigned short* __restrict__ wT, int N, int total) {
  int i = blockIdx.x * blockDim.x + threadIdx.x;
  if (i >= total) return;
  int n = i >> 9, k = i & 511;
  wT[i] = f2bf(w[(size_t)k * N + n]);
}

// ---------------- GEMM: C = A[M,K] * BT[N,K]^T + bias ----------------
// 128x128 block tile, BK=32, 4 waves (each a 64x64 quadrant), 16x16x32 MFMA.
// EPI==0: QKV epilogue (q/k -> [B*H][T][64], V -> transposed [B*H][64][T])
// EPI==1: fp32 output [M][512] with bias
template <int EPI>
__global__ __launch_bounds__(256) void gemm_bt(
    const unsigned short* __restrict__ A,
    const unsigned short* __restrict__ BT,
    const float* __restrict__ bias,
    float* __restrict__ outf,
    unsigned short* __restrict__ oq,
    unsigned short* __restrict__ ok,
    unsigned short* __restrict__ ovT,
    int K) {
  __shared__ alignas(16) unsigned short As[128 * 32];
  __shared__ alignas(16) unsigned short Bs[128 * 32];

  const int t = threadIdx.x;
  const int lane = t & 63;
  const int w = t >> 6;
  const int wr = (w >> 1) * 64;
  const int wc = (w & 1) * 64;
  const int g = lane >> 4, c = lane & 15;
  const int row0 = blockIdx.y * 128, col0 = blockIdx.x * 128;

  const int crow = t >> 2;          // 0..63
  const int ccol = (t & 3) * 8;     // 0,8,16,24
  const unsigned short* Ag0 = A + (size_t)(row0 + crow) * K + ccol;
  const unsigned short* Ag1 = A + (size_t)(row0 + 64 + crow) * K + ccol;
  const unsigned short* Bg0 = BT + (size_t)(col0 + crow) * K + ccol;
  const unsigned short* Bg1 = BT + (size_t)(col0 + 64 + crow) * K + ccol;

  f32x4 acc[4][4] = {};

  for (int k0 = 0; k0 < K; k0 += 32) {
    int4 a0 = *(const int4*)(Ag0 + k0);
    int4 a1 = *(const int4*)(Ag1 + k0);
    int4 b0 = *(const int4*)(Bg0 + k0);
    int4 b1 = *(const int4*)(Bg1 + k0);
    __syncthreads();
    *(int4*)&As[crow * 32 + ccol] = a0;
    *(int4*)&As[(64 + crow) * 32 + ccol] = a1;
    *(int4*)&Bs[crow * 32 + ccol] = b0;
    *(int4*)&Bs[(64 + crow) * 32 + ccol] = b1;
    __syncthreads();

    bf16x8 af[4], bfr[4];
#pragma unroll
    for (int m = 0; m < 4; ++m)
      af[m] = *(const bf16x8*)&As[(wr + m * 16 + c) * 32 + g * 8];
#pragma unroll
    for (int n = 0; n < 4; ++n)
      bfr[n] = *(const bf16x8*)&Bs[(wc + n * 16 + c) * 32 + g * 8];
#pragma unroll
    for (int m = 0; m < 4; ++m)
#pragma unroll
      for (int n = 0; n < 4; ++n)
        acc[m][n] = MFMA16(af[m], bfr[n], acc[m][n]);
  }

  // epilogue. D layout: row = g*4 + i, col = c (verified m89/m91 mapping)
#pragma unroll
  for (int m = 0; m < 4; ++m) {
#pragma unroll
    for (int n = 0; n < 4; ++n) {
      const int col = col0 + wc + n * 16 + c;
      const float bv = bias[col];
      if constexpr (EPI == 0) {
        const int which = col >> 9;          // wave-uniform (depends on block,n)
        const int h = (col >> 6) & 7;
        const int dh = col & 63;
        const int r0 = row0 + wr + m * 16 + g * 4;
        const int bb = r0 >> 12;             // r0 / T_SEQ (4 rows never cross)
        const int tt0 = r0 & 4095;
        if (which == 2) {
          // V transposed: vT[(bb*H + h)*64 + dh][tt0..tt0+3] -- contiguous
          ushort4 pk;
          pk.x = f2bf(acc[m][n][0] + bv);
          pk.y = f2bf(acc[m][n][1] + bv);
          pk.z = f2bf(acc[m][n][2] + bv);
          pk.w = f2bf(acc[m][n][3] + bv);
          *(ushort4*)&ovT[((size_t)((bb * NHEADS + h) * DH + dh)) * T_SEQ + tt0] = pk;
        } else {
          unsigned short* dst = (which == 0) ? oq : ok;
          const float sc = (which == 0) ? SCALE_Q : 1.0f;
#pragma unroll
          for (int i = 0; i < 4; ++i) {
            const size_t idx =
                ((size_t)((bb * NHEADS + h) * T_SEQ + tt0 + i)) * DH + dh;
            dst[idx] = f2bf((acc[m][n][i] + bv) * sc);
          }
        }
      } else {
#pragma unroll
        for (int i = 0; i < 4; ++i) {
          const int row = row0 + wr + m * 16 + g * 4 + i;
          outf[(size_t)row * 512 + col] = acc[m][n][i] + bv;
        }
      }
    }
  }
}

// ---------------- flash attention (causal) ----------------
// grid (B*H, T/64). 4 waves/block, each wave owns 16 q-rows. KV tiles of 64
// staged block-wide in LDS via global_load_lds, double-buffered, XOR-swizzled.
// QK^T computed SWAPPED (mfma(K,Q)) so each lane owns one q-row (q = c):
// row max/sum are 15 local ops + 2 shuffles; mi/li are scalars; P packed
// b64 stores. Defer-max (THR=8) skips rescale on most tiles.
__global__ __launch_bounds__(256) void attn_kernel(
    const unsigned short* __restrict__ qb,
    const unsigned short* __restrict__ kb,
    const unsigned short* __restrict__ vtb,
    unsigned short* __restrict__ yb) {
  const int bh = blockIdx.x;
  const int y = blockIdx.y;
  // causal load-balance: interleave heavy (large qblk) and light blocks
  const int qblk = (y & 1) ? (63 - (y >> 1)) : (y >> 1);
  const int w = threadIdx.x >> 6;
  const int lane = threadIdx.x & 63;
  const int g = lane >> 4, c = lane & 15;
  const int qw0 = qblk * 64 + w * 16;

  // K tile: rows = key (64), cols = d (64, 128B). V tile: rows = d, cols = t.
  __shared__ alignas(16) unsigned short Ks[2][64 * 64];
  __shared__ alignas(16) unsigned short Vs[2][64 * 64];
  __shared__ alignas(16) unsigned short Plds[4][16 * 64];

  const unsigned short* Qp  = qb + (size_t)bh * T_SEQ * DH;
  const unsigned short* Kp  = kb + (size_t)bh * T_SEQ * DH;
  const unsigned short* VTp = vtb + (size_t)bh * DH * T_SEQ;

  // staging: wave w stages LDS rows 16w..16w+15 of both tiles (2 gloads each).
  // source column pre-swizzled: row r keeps byte-col cb at cb ^ ((r&7)<<4);
  // gload instr writes rows q*8+l8 linearly, so swizzle = 8*(lc ^ l8) elems.
  const int l8 = lane >> 3, lc = lane & 7;
  const int swzE = 8 * (lc ^ l8);
  const unsigned short* Ksrc0 = Kp + (size_t)(16 * w + l8) * DH + swzE;
  const unsigned short* Ksrc1 = Kp + (size_t)(16 * w + 8 + l8) * DH + swzE;
  const unsigned short* Vsrc0 = VTp + (size_t)(16 * w + l8) * T_SEQ + swzE;
  const unsigned short* Vsrc1 = VTp + (size_t)(16 * w + 8 + l8) * T_SEQ + swzE;

#define STAGE(B, J0) do {                                              \
    gload16(Ksrc0 + (size_t)(J0) * DH, &Ks[B][(2 * w) * 512]);         \
    gload16(Ksrc1 + (size_t)(J0) * DH, &Ks[B][(2 * w + 1) * 512]);     \
    gload16(Vsrc0 + (J0), &Vs[B][(2 * w) * 512]);                      \
    gload16(Vsrc1 + (J0), &Vs[B][(2 * w + 1) * 512]);                  \
  } while (0)

  // Q fragments (B-operand of swapped QK^T): row = c, k = g*8.. (+32)
  bf16x8 qf0 = *(const bf16x8*)&Qp[(size_t)(qw0 + c) * DH + g * 8];
  bf16x8 qf1 = *(const bf16x8*)&Qp[(size_t)(qw0 + c) * DH + 32 + g * 8];

  f32x4 acc[4] = {};
  float mi = NEG_INF;   // running row-max for q = qw0 + c (exp2 domain)
  float li = 0.f;       // running row-sum for q = qw0 + c

  const int nt = qblk + 1;  // all waves run the same tile count, mask handles tail
  STAGE(0, 0);
  __syncthreads();  // compiler drains vmcnt(0) before s_barrier
  int cur = 0;
  const int swb = (c & 7) << 4;  // read-side xor (bytes)
  char* Pw = (char*)&Plds[w][0];

  for (int t = 0; t < nt; ++t) {
    if (t + 1 < nt) STAGE(cur ^ 1, (t + 1) * 64);

    const char* Kb = (const char*)&Ks[cur][0];
    const char* Vb = (const char*)&Vs[cur][0];

    // S tile (SWAPPED): s[ks][i] = S[key = t*64+ks*16+g*4+i][q = qw0+c]
    f32x4 s[4];
#pragma unroll
    for (int ks = 0; ks < 4; ++ks) {
      const int rb = (ks * 16 + c) * 128;
      bf16x8 kf0 = *(const bf16x8*)(Kb + rb + ((16 * g) ^ swb));
      bf16x8 kf1 = *(const bf16x8*)(Kb + rb + ((64 + 16 * g) ^ swb));
      f32x4 z = {0.f, 0.f, 0.f, 0.f};
      z = MFMA16(kf0, qf0, z);
      z = MFMA16(kf1, qf1, z);
      s[ks] = z;
    }

    // V fragments early -- independent of softmax, overlap ds latency
    bf16x8 vf0[4], vf1[4];
#pragma unroll
    for (int dt = 0; dt < 4; ++dt) {
      const int rb = (dt * 16 + c) * 128;
      vf0[dt] = *(const bf16x8*)(Vb + rb + ((16 * g) ^ swb));
      vf1[dt] = *(const bf16x8*)(Vb + rb + ((64 + 16 * g) ^ swb));
    }

    if (t == qblk) {  // diagonal tile: causal mask (key > q)
      const int qq = qw0 + c;
#pragma unroll
      for (int ks = 0; ks < 4; ++ks)
#pragma unroll
        for (int i = 0; i < 4; ++i) {
          const int key = t * 64 + ks * 16 + g * 4 + i;
          if (key > qq) s[ks][i] = NEG_INF;
        }
    }

    // row max: 15 local fmax + 2 cross-g shuffles (replicated over g)
    float m0 = fmaxf(fmaxf(s[0][0], s[0][1]), fmaxf(s[0][2], s[0][3]));
    float m1 = fmaxf(fmaxf(s[1][0], s[1][1]), fmaxf(s[1][2], s[1][3]));
    float m2 = fmaxf(fmaxf(s[2][0], s[2][1]), fmaxf(s[2][2], s[2][3]));
    float m3 = fmaxf(fmaxf(s[3][0], s[3][1]), fmaxf(s[3][2], s[3][3]));
    float mloc = fmaxf(fmaxf(m0, m1), fmaxf(m2, m3));
    mloc = fmaxf(mloc, __shfl_xor(mloc, 16));
    mloc = fmaxf(mloc, __shfl_xor(mloc, 32));

    // defer-max: only rescale when some row grew past THR=8
    if (__ballot(mloc > mi + 8.0f) != 0ull) {
      const float mn = fmaxf(mi, mloc);
      const float scq = exp2f(mi - mn);
      mi = mn;
      li *= scq;
      // redistribute sc to the acc layout (q = g*4+i lives at lane 4g+i)
      const float sv0 = __shfl(scq, 4 * g + 0);
      const float sv1 = __shfl(scq, 4 * g + 1);
      const float sv2 = __shfl(scq, 4 * g + 2);
      const float sv3 = __shfl(scq, 4 * g + 3);
#pragma unroll
      for (int dt = 0; dt < 4; ++dt) {
        acc[dt][0] *= sv0; acc[dt][1] *= sv1;
        acc[dt][2] *= sv2; acc[dt][3] *= sv3;
      }
    }

    // p = exp2(s - mi), local sum, packed bf16 stores (4 x 8B per lane)
    float ls = 0.f;
#pragma unroll
    for (int ks = 0; ks < 4; ++ks) {
      float p0 = exp2f(s[ks][0] - mi);
      float p1 = exp2f(s[ks][1] - mi);
      float p2 = exp2f(s[ks][2] - mi);
      float p3 = exp2f(s[ks][3] - mi);
      ls += (p0 + p1) + (p2 + p3);
      uint2 pk;
      pk.x = pack_bf2(p0, p1);
      pk.y = pack_bf2(p2, p3);
      // keys 16ks+4g..+3 of row q=c, swizzled with the same involution
      *(uint2*)(Pw + c * 128 + ((32 * ks + 8 * g) ^ swb)) = pk;
    }
    ls += __shfl_xor(ls, 16);
    ls += __shfl_xor(ls, 32);
    li += ls;

    // wave-private LDS RAW: P stores must land before the A-frag read
    asm volatile("s_waitcnt lgkmcnt(0)" ::: "memory");

    bf16x8 pf0 = *(const bf16x8*)(Pw + c * 128 + ((16 * g) ^ swb));
    bf16x8 pf1 = *(const bf16x8*)(Pw + c * 128 + ((64 + 16 * g) ^ swb));

#pragma unroll
    for (int dt = 0; dt < 4; ++dt) {
      acc[dt] = MFMA16(pf0, vf0[dt], acc[dt]);
      acc[dt] = MFMA16(pf1, vf1[dt], acc[dt]);
    }

    // barrier: publishes prefetched tile (vmcnt drain) + protects buf reuse
    __syncthreads();
    cur ^= 1;
  }
#undef STAGE

  // normalize + store to y_flat[(b*T + q)*512 + h*64 + d] as bf16
  // li for q-row g*4+i lives at lane 4g+i
  const float liq0 = __shfl(li, 4 * g + 0);
  const float liq1 = __shfl(li, 4 * g + 1);
  const float liq2 = __shfl(li, 4 * g + 2);
  const float liq3 = __shfl(li, 4 * g + 3);
  const float inv[4] = {1.0f / liq0, 1.0f / liq1, 1.0f / liq2, 1.0f / liq3};
  const int bb = bh >> 3, h = bh & 7;
#pragma unroll
  for (int i = 0; i < 4; ++i) {
    const int qq = qw0 + g * 4 + i;
    const size_t base = ((size_t)(bb * T_SEQ + qq)) * 512 + h * DH;
#pragma unroll
    for (int dt = 0; dt < 4; ++dt)
      yb[base + dt * 16 + c] = f2bf(acc[dt][i] * inv[i]);
  }
}

// ---------------- launch ----------------
extern "C" void kernel_launch(void* const* d_in, const int* in_sizes, int n_in,
                              void* d_out, int out_size, void* d_ws, size_t ws_size,
                              hipStream_t stream) {
  const float* x     = (const float*)d_in[0];
  const float* w_qkv = (const float*)d_in[1];
  const float* b_qkv = (const float*)d_in[2];
  const float* w_out = (const float*)d_in[3];
  const float* b_out = (const float*)d_in[4];
  float* out = (float*)d_out;

  char* p = (char*)d_ws;
  unsigned short* xb    = (unsigned short*)p; p += (size_t)8192 * 512 * 2;
  unsigned short* wqkvT = (unsigned short*)p; p += (size_t)1536 * 512 * 2;
  unsigned short* woutT = (unsigned short*)p; p += (size_t)512 * 512 * 2;
  unsigned short* qbuf  = (unsigned short*)p; p += (size_t)16 * T_SEQ * DH * 2;
  unsigned short* kbuf  = (unsigned short*)p; p += (size_t)16 * T_SEQ * DH * 2;
  unsigned short* vtbuf = (unsigned short*)p; p += (size_t)16 * T_SEQ * DH * 2;
  unsigned short* ybuf  = (unsigned short*)p; p += (size_t)8192 * 512 * 2;

  cvt_x_kernel<<<4096, 256, 0, stream>>>(x, xb, 8192 * 512 / 4);
  cvt_T_kernel<<<3072, 256, 0, stream>>>(w_qkv, wqkvT, 1536, 1536 * 512);
  cvt_T_kernel<<<1024, 256, 0, stream>>>(w_out, woutT, 512, 512 * 512);

  // QKV projection: M=8192, N=1536, K=512
  gemm_bt<0><<<dim3(12, 64), 256, 0, stream>>>(xb, wqkvT, b_qkv, nullptr,
                                               qbuf, kbuf, vtbuf, 512);
  // attention
  attn_kernel<<<dim3(16, 64), 256, 0, stream>>>(qbuf, kbuf, vtbuf, ybuf);
  // output projection: M=8192, N=512, K=512
  gemm_bt<1><<<dim3(4, 64), 256, 0, stream>>>(ybuf, woutT, b_out, out,
                                              nullptr, nullptr, nullptr, 512);
}

// Round 8
// 159.479 us; speedup vs baseline: 2.6581x; 1.2385x over previous
//
#include <hip/hip_runtime.h>
#include <cstdint>
#include <cstddef>

// ---------------- types / helpers ----------------
typedef __attribute__((ext_vector_type(8))) __bf16 bf16x8;
typedef __attribute__((ext_vector_type(4))) float  f32x4;

#define MFMA16(a, b, c) __builtin_amdgcn_mfma_f32_16x16x32_bf16((a), (b), (c), 0, 0, 0)

#define T_SEQ 4096
#define NHEADS 8
#define DH 64
#define NEG_INF (-__builtin_huge_valf())
// 1/sqrt(64) * log2(e)  (softmax done in exp2 domain)
#define SCALE_Q 0.18033688011112042f

__device__ __forceinline__ unsigned short f2bf(float f) {
  unsigned int u = __float_as_uint(f);
  u += 0x7fffu + ((u >> 16) & 1u);
  return (unsigned short)(u >> 16);
}

// pack two f32 -> two bf16 in one u32 (round-half-up; a = low half)
__device__ __forceinline__ unsigned int pack_bf2(float a, float b) {
  unsigned int au = __float_as_uint(a) + 0x8000u;
  unsigned int bu = __float_as_uint(b) + 0x8000u;
  return (au >> 16) | (bu & 0xffff0000u);
}

// async global->LDS, 16B per lane. LDS dest = uniform base + lane*16.
__device__ __forceinline__ void gload16(const unsigned short* g, unsigned short* l) {
  __builtin_amdgcn_global_load_lds(
      (const __attribute__((address_space(1))) unsigned short*)g,
      (__attribute__((address_space(3))) unsigned short*)l, 16, 0, 0);
}

// ---------------- conversion kernels ----------------
__global__ void cvt_x_kernel(const float* __restrict__ x,
                             unsigned short* __restrict__ xb, int n4) {
  int i = blockIdx.x * blockDim.x + threadIdx.x;
  if (i >= n4) return;
  float4 v = ((const float4*)x)[i];
  ushort4 o;
  o.x = f2bf(v.x); o.y = f2bf(v.y); o.z = f2bf(v.z); o.w = f2bf(v.w);
  ((ushort4*)xb)[i] = o;
}

// w [512][N] (K=512 rows) -> wT [N][512] bf16
__global__ void cvt_T_kernel(const float* __restrict__ w,
                             unsigned short* __restrict__ wT, int N, int total) {
  int i = blockIdx.x * blockDim.x + threadIdx.x;
  if (i >= total) return;
  int n = i >> 9, k = i & 511;
  wT[i] = f2bf(w[(size_t)k * N + n]);
}

// ---------------- GEMM: C = A[M,K] * BT[N,K]^T + bias ----------------
// 128x128 block tile, BK=32, 4 waves (each a 64x64 quadrant), 16x16x32 MFMA.
// EPI==0: QKV epilogue (q/k -> [B*H][T][64], V -> transposed [B*H][64][T])
// EPI==1: fp32 output [M][512] with bias
template <int EPI>
__global__ __launch_bounds__(256) void gemm_bt(
    const unsigned short* __restrict__ A,
    const unsigned short* __restrict__ BT,
    const float* __restrict__ bias,
    float* __restrict__ outf,
    unsigned short* __restrict__ oq,
    unsigned short* __restrict__ ok,
    unsigned short* __restrict__ ovT,
    int K) {
  __shared__ alignas(16) unsigned short As[128 * 32];
  __shared__ alignas(16) unsigned short Bs[128 * 32];

  const int t = threadIdx.x;
  const int lane = t & 63;
  const int w = t >> 6;
  const int wr = (w >> 1) * 64;
  const int wc = (w & 1) * 64;
  const int g = lane >> 4, c = lane & 15;
  const int row0 = blockIdx.y * 128, col0 = blockIdx.x * 128;

  const int crow = t >> 2;          // 0..63
  const int ccol = (t & 3) * 8;     // 0,8,16,24
  const unsigned short* Ag0 = A + (size_t)(row0 + crow) * K + ccol;
  const unsigned short* Ag1 = A + (size_t)(row0 + 64 + crow) * K + ccol;
  const unsigned short* Bg0 = BT + (size_t)(col0 + crow) * K + ccol;
  const unsigned short* Bg1 = BT + (size_t)(col0 + 64 + crow) * K + ccol;

  f32x4 acc[4][4] = {};

  for (int k0 = 0; k0 < K; k0 += 32) {
    int4 a0 = *(const int4*)(Ag0 + k0);
    int4 a1 = *(const int4*)(Ag1 + k0);
    int4 b0 = *(const int4*)(Bg0 + k0);
    int4 b1 = *(const int4*)(Bg1 + k0);
    __syncthreads();
    *(int4*)&As[crow * 32 + ccol] = a0;
    *(int4*)&As[(64 + crow) * 32 + ccol] = a1;
    *(int4*)&Bs[crow * 32 + ccol] = b0;
    *(int4*)&Bs[(64 + crow) * 32 + ccol] = b1;
    __syncthreads();

    bf16x8 af[4], bfr[4];
#pragma unroll
    for (int m = 0; m < 4; ++m)
      af[m] = *(const bf16x8*)&As[(wr + m * 16 + c) * 32 + g * 8];
#pragma unroll
    for (int n = 0; n < 4; ++n)
      bfr[n] = *(const bf16x8*)&Bs[(wc + n * 16 + c) * 32 + g * 8];
#pragma unroll
    for (int m = 0; m < 4; ++m)
#pragma unroll
      for (int n = 0; n < 4; ++n)
        acc[m][n] = MFMA16(af[m], bfr[n], acc[m][n]);
  }

  // epilogue. D layout: row = g*4 + i, col = c (verified m89/m91 mapping)
#pragma unroll
  for (int m = 0; m < 4; ++m) {
#pragma unroll
    for (int n = 0; n < 4; ++n) {
      const int col = col0 + wc + n * 16 + c;
      const float bv = bias[col];
      if constexpr (EPI == 0) {
        const int which = col >> 9;          // wave-uniform (depends on block,n)
        const int h = (col >> 6) & 7;
        const int dh = col & 63;
        const int r0 = row0 + wr + m * 16 + g * 4;
        const int bb = r0 >> 12;             // r0 / T_SEQ (4 rows never cross)
        const int tt0 = r0 & 4095;
        if (which == 2) {
          // V transposed: vT[(bb*H + h)*64 + dh][tt0..tt0+3] -- contiguous
          ushort4 pk;
          pk.x = f2bf(acc[m][n][0] + bv);
          pk.y = f2bf(acc[m][n][1] + bv);
          pk.z = f2bf(acc[m][n][2] + bv);
          pk.w = f2bf(acc[m][n][3] + bv);
          *(ushort4*)&ovT[((size_t)((bb * NHEADS + h) * DH + dh)) * T_SEQ + tt0] = pk;
        } else {
          unsigned short* dst = (which == 0) ? oq : ok;
          const float sc = (which == 0) ? SCALE_Q : 1.0f;
#pragma unroll
          for (int i = 0; i < 4; ++i) {
            const size_t idx =
                ((size_t)((bb * NHEADS + h) * T_SEQ + tt0 + i)) * DH + dh;
            dst[idx] = f2bf((acc[m][n][i] + bv) * sc);
          }
        }
      } else {
#pragma unroll
        for (int i = 0; i < 4; ++i) {
          const int row = row0 + wr + m * 16 + g * 4 + i;
          outf[(size_t)row * 512 + col] = acc[m][n][i] + bv;
        }
      }
    }
  }
}

// ---------------- flash attention (causal) ----------------
// grid (B*H, 32). Each block runs TWO flash passes: q-block y and q-block
// 63-y -- (y+1) + (64-y) = 65 tiles for EVERY block, so all blocks finish
// together (the whole grid is co-resident; unequal blocks would leave CUs
// idle during the drain). 4 waves/block, 16 q-rows/wave, KV tiles of 64
// staged via global_load_lds, double-buffered, XOR-swizzled. Swapped QK^T
// (mfma(K,Q)): each lane owns one q-row; softmax is local ops + 2 shuffles.
__global__ __launch_bounds__(256) void attn_kernel(
    const unsigned short* __restrict__ qb,
    const unsigned short* __restrict__ kb,
    const unsigned short* __restrict__ vtb,
    unsigned short* __restrict__ yb) {
  const int bh = blockIdx.x;
  const int y = blockIdx.y;
  const int w = threadIdx.x >> 6;
  const int lane = threadIdx.x & 63;
  const int g = lane >> 4, c = lane & 15;

  // K tile: rows = key (64), cols = d (64, 128B). V tile: rows = d, cols = t.
  __shared__ alignas(16) unsigned short Ks[2][64 * 64];
  __shared__ alignas(16) unsigned short Vs[2][64 * 64];
  __shared__ alignas(16) unsigned short Plds[4][16 * 64];

  const unsigned short* Qp  = qb + (size_t)bh * T_SEQ * DH;
  const unsigned short* Kp  = kb + (size_t)bh * T_SEQ * DH;
  const unsigned short* VTp = vtb + (size_t)bh * DH * T_SEQ;

  // staging: wave w stages LDS rows 16w..16w+15 of both tiles (2 gloads each).
  // source column pre-swizzled: row r keeps byte-col cb at cb ^ ((r&7)<<4);
  // gload instr writes rows q*8+l8 linearly, so swizzle = 8*(lc ^ l8) elems.
  const int l8 = lane >> 3, lc = lane & 7;
  const int swzE = 8 * (lc ^ l8);
  const unsigned short* Ksrc0 = Kp + (size_t)(16 * w + l8) * DH + swzE;
  const unsigned short* Ksrc1 = Kp + (size_t)(16 * w + 8 + l8) * DH + swzE;
  const unsigned short* Vsrc0 = VTp + (size_t)(16 * w + l8) * T_SEQ + swzE;
  const unsigned short* Vsrc1 = VTp + (size_t)(16 * w + 8 + l8) * T_SEQ + swzE;

#define STAGE(B, J0) do {                                              \
    gload16(Ksrc0 + (size_t)(J0) * DH, &Ks[B][(2 * w) * 512]);         \
    gload16(Ksrc1 + (size_t)(J0) * DH, &Ks[B][(2 * w + 1) * 512]);     \
    gload16(Vsrc0 + (J0), &Vs[B][(2 * w) * 512]);                      \
    gload16(Vsrc1 + (J0), &Vs[B][(2 * w + 1) * 512]);                  \
  } while (0)

  const int swb = (c & 7) << 4;  // read-side xor (bytes)
  char* Pw = (char*)&Plds[w][0];
  const int bb = bh >> 3, h = bh & 7;

  for (int pass = 0; pass < 2; ++pass) {
    const int qblk = pass ? (63 - y) : y;
    const int qw0 = qblk * 64 + w * 16;

    // Q fragments (B-operand of swapped QK^T): row = c, k = g*8.. (+32)
    bf16x8 qf0 = *(const bf16x8*)&Qp[(size_t)(qw0 + c) * DH + g * 8];
    bf16x8 qf1 = *(const bf16x8*)&Qp[(size_t)(qw0 + c) * DH + 32 + g * 8];

    f32x4 acc[4] = {};
    float mi = NEG_INF;   // running row-max for q = qw0 + c (exp2 domain)
    float li = 0.f;       // running row-sum for q = qw0 + c

    const int nt = qblk + 1;  // same tile count for all waves; mask = tail
    STAGE(0, 0);
    __syncthreads();  // compiler drains vmcnt(0) before s_barrier
    int cur = 0;

    for (int t = 0; t < nt; ++t) {
      if (t + 1 < nt) STAGE(cur ^ 1, (t + 1) * 64);

      const char* Kb = (const char*)&Ks[cur][0];
      const char* Vb = (const char*)&Vs[cur][0];

      // S tile (SWAPPED): s[ks][i] = S[key = t*64+ks*16+g*4+i][q = qw0+c]
      f32x4 s[4];
#pragma unroll
      for (int ks = 0; ks < 4; ++ks) {
        const int rb = (ks * 16 + c) * 128;
        bf16x8 kf0 = *(const bf16x8*)(Kb + rb + ((16 * g) ^ swb));
        bf16x8 kf1 = *(const bf16x8*)(Kb + rb + ((64 + 16 * g) ^ swb));
        f32x4 z = {0.f, 0.f, 0.f, 0.f};
        z = MFMA16(kf0, qf0, z);
        z = MFMA16(kf1, qf1, z);
        s[ks] = z;
      }

      // V fragments early -- independent of softmax, overlap ds latency
      bf16x8 vf0[4], vf1[4];
#pragma unroll
      for (int dt = 0; dt < 4; ++dt) {
        const int rb = (dt * 16 + c) * 128;
        vf0[dt] = *(const bf16x8*)(Vb + rb + ((16 * g) ^ swb));
        vf1[dt] = *(const bf16x8*)(Vb + rb + ((64 + 16 * g) ^ swb));
      }

      if (t == qblk) {  // diagonal tile: causal mask (key > q)
        const int qq = qw0 + c;
#pragma unroll
        for (int ks = 0; ks < 4; ++ks)
#pragma unroll
          for (int i = 0; i < 4; ++i) {
            const int key = t * 64 + ks * 16 + g * 4 + i;
            if (key > qq) s[ks][i] = NEG_INF;
          }
      }

      // row max: 15 local fmax + 2 cross-g shuffles (replicated over g)
      float m0 = fmaxf(fmaxf(s[0][0], s[0][1]), fmaxf(s[0][2], s[0][3]));
      float m1 = fmaxf(fmaxf(s[1][0], s[1][1]), fmaxf(s[1][2], s[1][3]));
      float m2 = fmaxf(fmaxf(s[2][0], s[2][1]), fmaxf(s[2][2], s[2][3]));
      float m3 = fmaxf(fmaxf(s[3][0], s[3][1]), fmaxf(s[3][2], s[3][3]));
      float mloc = fmaxf(fmaxf(m0, m1), fmaxf(m2, m3));
      mloc = fmaxf(mloc, __shfl_xor(mloc, 16));
      mloc = fmaxf(mloc, __shfl_xor(mloc, 32));

      // defer-max: only rescale when some row grew past THR=8
      if (__ballot(mloc > mi + 8.0f) != 0ull) {
        const float mn = fmaxf(mi, mloc);
        const float scq = exp2f(mi - mn);
        mi = mn;
        li *= scq;
        // redistribute sc to the acc layout (q = g*4+i lives at lane 4g+i)
        const float sv0 = __shfl(scq, 4 * g + 0);
        const float sv1 = __shfl(scq, 4 * g + 1);
        const float sv2 = __shfl(scq, 4 * g + 2);
        const float sv3 = __shfl(scq, 4 * g + 3);
#pragma unroll
        for (int dt = 0; dt < 4; ++dt) {
          acc[dt][0] *= sv0; acc[dt][1] *= sv1;
          acc[dt][2] *= sv2; acc[dt][3] *= sv3;
        }
      }

      // p = exp2(s - mi), local sum, packed bf16 stores (4 x 8B per lane)
      float ls = 0.f;
#pragma unroll
      for (int ks = 0; ks < 4; ++ks) {
        float p0 = exp2f(s[ks][0] - mi);
        float p1 = exp2f(s[ks][1] - mi);
        float p2 = exp2f(s[ks][2] - mi);
        float p3 = exp2f(s[ks][3] - mi);
        ls += (p0 + p1) + (p2 + p3);
        uint2 pk;
        pk.x = pack_bf2(p0, p1);
        pk.y = pack_bf2(p2, p3);
        // keys 16ks+4g..+3 of row q=c, swizzled with the same involution
        *(uint2*)(Pw + c * 128 + ((32 * ks + 8 * g) ^ swb)) = pk;
      }
      ls += __shfl_xor(ls, 16);
      ls += __shfl_xor(ls, 32);
      li += ls;

      // wave-private LDS RAW: P stores must land before the A-frag read
      asm volatile("s_waitcnt lgkmcnt(0)" ::: "memory");

      bf16x8 pf0 = *(const bf16x8*)(Pw + c * 128 + ((16 * g) ^ swb));
      bf16x8 pf1 = *(const bf16x8*)(Pw + c * 128 + ((64 + 16 * g) ^ swb));

#pragma unroll
      for (int dt = 0; dt < 4; ++dt) {
        acc[dt] = MFMA16(pf0, vf0[dt], acc[dt]);
        acc[dt] = MFMA16(pf1, vf1[dt], acc[dt]);
      }

      // barrier: publishes prefetched tile (vmcnt drain) + protects buf reuse
      __syncthreads();
      cur ^= 1;
    }

    // normalize + store to y_flat[(b*T + q)*512 + h*64 + d] as bf16
    // li for q-row g*4+i lives at lane 4g+i
    const float liq0 = __shfl(li, 4 * g + 0);
    const float liq1 = __shfl(li, 4 * g + 1);
    const float liq2 = __shfl(li, 4 * g + 2);
    const float liq3 = __shfl(li, 4 * g + 3);
    const float inv[4] = {1.0f / liq0, 1.0f / liq1, 1.0f / liq2, 1.0f / liq3};
#pragma unroll
    for (int i = 0; i < 4; ++i) {
      const int qq = qw0 + g * 4 + i;
      const size_t base = ((size_t)(bb * T_SEQ + qq)) * 512 + h * DH;
#pragma unroll
      for (int dt = 0; dt < 4; ++dt)
        yb[base + dt * 16 + c] = f2bf(acc[dt][i] * inv[i]);
    }
  }
#undef STAGE
}

// ---------------- launch ----------------
extern "C" void kernel_launch(void* const* d_in, const int* in_sizes, int n_in,
                              void* d_out, int out_size, void* d_ws, size_t ws_size,
                              hipStream_t stream) {
  const float* x     = (const float*)d_in[0];
  const float* w_qkv = (const float*)d_in[1];
  const float* b_qkv = (const float*)d_in[2];
  const float* w_out = (const float*)d_in[3];
  const float* b_out = (const float*)d_in[4];
  float* out = (float*)d_out;

  char* p = (char*)d_ws;
  unsigned short* xb    = (unsigned short*)p; p += (size_t)8192 * 512 * 2;
  unsigned short* wqkvT = (unsigned short*)p; p += (size_t)1536 * 512 * 2;
  unsigned short* woutT = (unsigned short*)p; p += (size_t)512 * 512 * 2;
  unsigned short* qbuf  = (unsigned short*)p; p += (size_t)16 * T_SEQ * DH * 2;
  unsigned short* kbuf  = (unsigned short*)p; p += (size_t)16 * T_SEQ * DH * 2;
  unsigned short* vtbuf = (unsigned short*)p; p += (size_t)16 * T_SEQ * DH * 2;
  unsigned short* ybuf  = (unsigned short*)p; p += (size_t)8192 * 512 * 2;

  cvt_x_kernel<<<4096, 256, 0, stream>>>(x, xb, 8192 * 512 / 4);
  cvt_T_kernel<<<3072, 256, 0, stream>>>(w_qkv, wqkvT, 1536, 1536 * 512);
  cvt_T_kernel<<<1024, 256, 0, stream>>>(w_out, woutT, 512, 512 * 512);

  // QKV projection: M=8192, N=1536, K=512
  gemm_bt<0><<<dim3(12, 64), 256, 0, stream>>>(xb, wqkvT, b_qkv, nullptr,
                                               qbuf, kbuf, vtbuf, 512);
  // attention (paired q-blocks: every block runs exactly 65 tiles)
  attn_kernel<<<dim3(16, 32), 256, 0, stream>>>(qbuf, kbuf, vtbuf, ybuf);
  // output projection: M=8192, N=512, K=512
  gemm_bt<1><<<dim3(4, 64), 256, 0, stream>>>(ybuf, woutT, b_out, out,
                                              nullptr, nullptr, nullptr, 512);
}